// Round 1
// baseline (1238.695 us; speedup 1.0000x reference)
//
#include <hip/hip_runtime.h>
#include <math.h>

#define NEG_SLOPE 0.2f

// ---------------------------------------------------------------------------
// GEMM + attention logits: H[n, 64] = X[n, K] @ W[K, 64]
//   As[n] = dot(H[n,:], att_s); Ad[n] = dot(H[n,:], att_d)
// One wave per node; lane = output feature j. W staged in LDS as [k][j]
// (lanes j consecutive -> 2-way bank alias, free). x row broadcast via
// __shfl with uniform k (v_readlane).
// ---------------------------------------------------------------------------
template <int K>
__global__ __launch_bounds__(256) void gemm_att(
    const float* __restrict__ X, const float* __restrict__ W,
    const float* __restrict__ att_s, const float* __restrict__ att_d,
    float* __restrict__ H, float* __restrict__ As, float* __restrict__ Ad,
    int n)
{
    __shared__ float Ws[K * 64];
    for (int i = threadIdx.x; i < K * 64; i += 256) Ws[i] = W[i];
    __syncthreads();

    const int lane = threadIdx.x & 63;
    const int wv = threadIdx.x >> 6;
    const float ats = att_s[lane];
    const float atd = att_d[lane];

    for (int node = blockIdx.x * 4 + wv; node < n; node += gridDim.x * 4) {
        const float* xr = X + (size_t)node * K;
        float x0 = xr[lane];
        float x1 = (K > 64) ? xr[64 + lane] : 0.0f;
        float acc = 0.0f;
#pragma unroll
        for (int k = 0; k < 64; ++k)
            acc = fmaf(__shfl(x0, k), Ws[k * 64 + lane], acc);
        if (K > 64) {
#pragma unroll
            for (int k = 0; k < 64; ++k)
                acc = fmaf(__shfl(x1, k), Ws[(k + 64) * 64 + lane], acc);
        }
        H[(size_t)node * 64 + lane] = acc;
        float vs = acc * ats;
        float vd = acc * atd;
#pragma unroll
        for (int off = 32; off; off >>= 1) {
            vs += __shfl_xor(vs, off);
            vd += __shfl_xor(vd, off);
        }
        if (lane == 0) { As[node] = vs; Ad[node] = vd; }
    }
}

// ---------------------------------------------------------------------------
// CSR build: histogram -> scan -> scatter
// ---------------------------------------------------------------------------
__global__ void hist_kernel(const int* __restrict__ dst, int e, int* __restrict__ deg)
{
    int i = blockIdx.x * blockDim.x + threadIdx.x;
    if (i < e) atomicAdd(&deg[dst[i]], 1);
}

#define SCAN_B 256
#define SCAN_E 1024  // 4 elems per thread

__global__ __launch_bounds__(SCAN_B) void scan1_kernel(
    const int* __restrict__ deg, int n, int* __restrict__ out /* = rp+1 */,
    int* __restrict__ partials)
{
    __shared__ int sh[SCAN_B];
    const int b = blockIdx.x, t = threadIdx.x;
    const int base = b * SCAN_E + t * 4;
    int v[4];
#pragma unroll
    for (int i = 0; i < 4; ++i) {
        int idx = base + i;
        v[i] = (idx < n) ? deg[idx] : 0;
    }
    v[1] += v[0]; v[2] += v[1]; v[3] += v[2];
    sh[t] = v[3];
    __syncthreads();
    for (int off = 1; off < SCAN_B; off <<= 1) {
        int x = (t >= off) ? sh[t - off] : 0;
        __syncthreads();
        sh[t] += x;
        __syncthreads();
    }
    int excl = (t > 0) ? sh[t - 1] : 0;
#pragma unroll
    for (int i = 0; i < 4; ++i) {
        int idx = base + i;
        if (idx < n) out[idx] = v[i] + excl;  // inclusive scan
    }
    if (t == SCAN_B - 1) partials[b] = sh[t];
}

__global__ void scan2_kernel(int* __restrict__ partials, int nb)
{
    if (threadIdx.x == 0 && blockIdx.x == 0) {
        int run = 0;
        for (int i = 0; i < nb; ++i) {
            int v = partials[i];
            partials[i] = run;
            run += v;
        }
    }
}

__global__ void scan3_kernel(int* __restrict__ rp, int n, const int* __restrict__ partials)
{
    int i = blockIdx.x * blockDim.x + threadIdx.x;
    if (i < n) rp[1 + i] += partials[i >> 10];
    if (i == 0) rp[0] = 0;
}

__global__ void cursor_kernel(const int* __restrict__ rp, int* __restrict__ cursor, int n)
{
    int i = blockIdx.x * blockDim.x + threadIdx.x;
    if (i < n) cursor[i] = rp[i];
}

__global__ void scatter_kernel(const int* __restrict__ src, const int* __restrict__ dst,
                               int e, int* __restrict__ cursor, int* __restrict__ sorted)
{
    int i = blockIdx.x * blockDim.x + threadIdx.x;
    if (i < e) {
        int d = dst[i];
        int pos = atomicAdd(&cursor[d], 1);
        sorted[pos] = src[i];
    }
}

// ---------------------------------------------------------------------------
// Aggregation: one wave per destination node. Segment softmax (max, sum,
// weighted accumulate) recomputing e = leaky_relu(a_src[s] + a_dst[d]).
// Bias (+ optional ReLU) fused into epilogue.
// ---------------------------------------------------------------------------
__global__ __launch_bounds__(256) void aggr_kernel(
    const int* __restrict__ rp, const int* __restrict__ sorted,
    const float* __restrict__ As, const float* __restrict__ Ad,
    const float* __restrict__ Hin, const float* __restrict__ bias,
    float* __restrict__ Out, int n, int relu_flag)
{
    const int lane = threadIdx.x & 63;
    const int wv = threadIdx.x >> 6;
    const float b = bias[lane];

    for (int d = blockIdx.x * 4 + wv; d < n; d += gridDim.x * 4) {
        const int beg = rp[d], end = rp[d + 1];
        const float ad = Ad[d];

        float lmax = -INFINITY;
        for (int i = beg + lane; i < end; i += 64) {
            float e = As[sorted[i]] + ad;
            e = (e >= 0.0f) ? e : NEG_SLOPE * e;
            lmax = fmaxf(lmax, e);
        }
#pragma unroll
        for (int off = 32; off; off >>= 1) lmax = fmaxf(lmax, __shfl_xor(lmax, off));

        float lsum = 0.0f;
        for (int i = beg + lane; i < end; i += 64) {
            float e = As[sorted[i]] + ad;
            e = (e >= 0.0f) ? e : NEG_SLOPE * e;
            lsum += __expf(e - lmax);
        }
#pragma unroll
        for (int off = 32; off; off >>= 1) lsum += __shfl_xor(lsum, off);

        const float inv = 1.0f / (lsum + 1e-16f);

        float acc = 0.0f;
        for (int i = beg; i < end; ++i) {
            int s = sorted[i];
            float e = As[s] + ad;
            e = (e >= 0.0f) ? e : NEG_SLOPE * e;
            float w = __expf(e - lmax) * inv;
            acc = fmaf(w, Hin[(size_t)s * 64 + lane], acc);
        }

        float r = acc + b;
        if (relu_flag) r = fmaxf(r, 0.0f);
        Out[(size_t)d * 64 + lane] = r;
    }
}

// ---------------------------------------------------------------------------
// Final linear [64 -> 32] + log_softmax. 2 nodes per wave (width-32 groups).
// ---------------------------------------------------------------------------
__global__ __launch_bounds__(256) void lin_lsm_kernel(
    const float* __restrict__ Z, const float* __restrict__ Wl,
    const float* __restrict__ bl, float* __restrict__ out, int n)
{
    __shared__ float Ws[64 * 32];
    __shared__ float bs[32];
    for (int i = threadIdx.x; i < 64 * 32; i += 256) Ws[i] = Wl[i];
    if (threadIdx.x < 32) bs[threadIdx.x] = bl[threadIdx.x];
    __syncthreads();

    const int lane = threadIdx.x & 63;
    const int wv = threadIdx.x >> 6;
    const int half = lane >> 5;
    const int o = lane & 31;

    for (int base = (blockIdx.x * 4 + wv) * 2; base < n; base += gridDim.x * 8) {
        const int nd = base + half;
        float acc = 0.0f;
        if (nd < n) {
            const float* z = Z + (size_t)nd * 64;
#pragma unroll
            for (int k = 0; k < 64; ++k)
                acc = fmaf(z[k], Ws[k * 32 + o], acc);
            acc += bs[o];
        }
        float m = acc;
#pragma unroll
        for (int off = 16; off; off >>= 1) m = fmaxf(m, __shfl_xor(m, off, 32));
        float ex = __expf(acc - m);
        float s = ex;
#pragma unroll
        for (int off = 16; off; off >>= 1) s += __shfl_xor(s, off, 32);
        if (nd < n) out[(size_t)nd * 32 + o] = acc - m - logf(s);
    }
}

// ---------------------------------------------------------------------------
extern "C" void kernel_launch(void* const* d_in, const int* in_sizes, int n_in,
                              void* d_out, int out_size, void* d_ws, size_t ws_size,
                              hipStream_t stream)
{
    const float* x        = (const float*)d_in[0];
    const int*   ei1      = (const int*)d_in[1];
    const int*   ei2      = (const int*)d_in[2];
    const float* W1       = (const float*)d_in[3];
    const float* att_src1 = (const float*)d_in[4];
    const float* att_dst1 = (const float*)d_in[5];
    const float* b1       = (const float*)d_in[6];
    const float* W2       = (const float*)d_in[7];
    const float* att_src2 = (const float*)d_in[8];
    const float* att_dst2 = (const float*)d_in[9];
    const float* b2       = (const float*)d_in[10];
    const float* Wlin     = (const float*)d_in[11];
    const float* blin     = (const float*)d_in[12];
    float* out = (float*)d_out;

    const int n = in_sizes[0] / 128;   // 100000
    const int e = in_sizes[1] / 2;     // 1600000

    // workspace layout
    size_t off = 0;
    auto alloc = [&](size_t bytes) {
        void* p = (char*)d_ws + off;
        off += (bytes + 255) & ~(size_t)255;
        return p;
    };
    float* bufH  = (float*)alloc((size_t)n * 64 * 4);
    float* bufZ  = (float*)alloc((size_t)n * 64 * 4);
    float* As    = (float*)alloc((size_t)n * 4);
    float* Ad    = (float*)alloc((size_t)n * 4);
    int* deg     = (int*)alloc((size_t)n * 4);
    int* rp      = (int*)alloc((size_t)(n + 1) * 4);
    int* cursor  = (int*)alloc((size_t)n * 4);
    int* partials= (int*)alloc(256 * 4);
    int* sorted  = (int*)alloc((size_t)e * 4);

    const int nb_scan = (n + SCAN_E - 1) / SCAN_E;
    const int gE = (e + 255) / 256;
    const int gN = (n + 255) / 256;
    const int gWave = (n + 3) / 4;      // one wave per node, 4 waves/block

    // ---------------- Layer 1 ----------------
    gemm_att<128><<<gWave, 256, 0, stream>>>(x, W1, att_src1, att_dst1, bufH, As, Ad, n);

    hipMemsetAsync(deg, 0, (size_t)n * 4, stream);
    hist_kernel<<<gE, 256, 0, stream>>>(ei1 + e, e, deg);
    scan1_kernel<<<nb_scan, SCAN_B, 0, stream>>>(deg, n, rp + 1, partials);
    scan2_kernel<<<1, 64, 0, stream>>>(partials, nb_scan);
    scan3_kernel<<<gN, 256, 0, stream>>>(rp, n, partials);
    cursor_kernel<<<gN, 256, 0, stream>>>(rp, cursor, n);
    scatter_kernel<<<gE, 256, 0, stream>>>(ei1, ei1 + e, e, cursor, sorted);

    aggr_kernel<<<gWave, 256, 0, stream>>>(rp, sorted, As, Ad, bufH, b1, bufZ, n, 1);

    // ---------------- Layer 2 ----------------
    gemm_att<64><<<gWave, 256, 0, stream>>>(bufZ, W2, att_src2, att_dst2, bufH, As, Ad, n);

    hipMemsetAsync(deg, 0, (size_t)n * 4, stream);
    hist_kernel<<<gE, 256, 0, stream>>>(ei2 + e, e, deg);
    scan1_kernel<<<nb_scan, SCAN_B, 0, stream>>>(deg, n, rp + 1, partials);
    scan2_kernel<<<1, 64, 0, stream>>>(partials, nb_scan);
    scan3_kernel<<<gN, 256, 0, stream>>>(rp, n, partials);
    cursor_kernel<<<gN, 256, 0, stream>>>(rp, cursor, n);
    scatter_kernel<<<gE, 256, 0, stream>>>(ei2, ei2 + e, e, cursor, sorted);

    aggr_kernel<<<gWave, 256, 0, stream>>>(rp, sorted, As, Ad, bufH, b2, bufZ, n, 0);

    // ---------------- Final linear + log_softmax ----------------
    const int gLSM = (n + 7) / 8;
    lin_lsm_kernel<<<gLSM, 256, 0, stream>>>(bufZ, Wlin, blin, out, n);
}

// Round 2
// 762.194 us; speedup vs baseline: 1.6252x; 1.6252x over previous
//
#include <hip/hip_runtime.h>
#include <math.h>

#define NEG_SLOPE 0.2f

// ---------------------------------------------------------------------------
// Register-tiled GEMM + fused attention logits.
//   H[n,64] = X[n,K] @ W[K,64];  As[n] = H.att_s;  Ad[n] = H.att_d
// Block: 256 threads -> tile 64 nodes x 64 features, per-thread 4x4 acc.
// Xs row-major with row stride K+4 (16B-aligned float4 reads, 2-way bank
// alias across the 4 ty rows = free). W staged in 64-k chunks (<=16KB) so
// total LDS stays <=50KB -> 3 blocks/CU.
// ---------------------------------------------------------------------------
template <int K>
__global__ __launch_bounds__(256) void gemm_tile(
    const float* __restrict__ X, const float* __restrict__ W,
    const float* __restrict__ att_s, const float* __restrict__ att_d,
    float* __restrict__ H, float* __restrict__ As, float* __restrict__ Ad,
    int n)
{
    constexpr int XP = K + 4;
    constexpr int BK = 64;
    __shared__ float Xs[64 * XP];
    __shared__ float Ws[BK * 64];

    const int tid = threadIdx.x;
    const int node0 = blockIdx.x * 64;

    // stage X tile: coalesced float4 reads, row-major padded writes
    for (int i4 = tid; i4 < 64 * (K / 4); i4 += 256) {
        int r = i4 / (K / 4);
        int c = (i4 % (K / 4)) * 4;
        int nd = node0 + r;
        float4 v = make_float4(0.f, 0.f, 0.f, 0.f);
        if (nd < n) v = *(const float4*)&X[(size_t)nd * K + c];
        *(float4*)&Xs[r * XP + c] = v;
    }

    const int tx = tid & 15;   // feature group: features tx*4..tx*4+3
    const int ty = tid >> 4;   // node group:    nodes   ty*4..ty*4+3

    float acc[4][4];
#pragma unroll
    for (int r = 0; r < 4; ++r)
#pragma unroll
        for (int f = 0; f < 4; ++f) acc[r][f] = 0.0f;

    for (int kc = 0; kc < K; kc += BK) {
        __syncthreads();
        for (int i = tid; i < BK * 64; i += 256) Ws[i] = W[kc * 64 + i];
        __syncthreads();

        for (int k = 0; k < BK; k += 4) {
            float4 a0 = *(const float4*)&Xs[(ty * 4 + 0) * XP + kc + k];
            float4 a1 = *(const float4*)&Xs[(ty * 4 + 1) * XP + kc + k];
            float4 a2 = *(const float4*)&Xs[(ty * 4 + 2) * XP + kc + k];
            float4 a3 = *(const float4*)&Xs[(ty * 4 + 3) * XP + kc + k];
            float4 b0 = *(const float4*)&Ws[(k + 0) * 64 + tx * 4];
            float4 b1 = *(const float4*)&Ws[(k + 1) * 64 + tx * 4];
            float4 b2 = *(const float4*)&Ws[(k + 2) * 64 + tx * 4];
            float4 b3 = *(const float4*)&Ws[(k + 3) * 64 + tx * 4];
#define GEMM_ROW(rr, av)                                                     \
            acc[rr][0] = fmaf(av.x, b0.x, acc[rr][0]);                       \
            acc[rr][1] = fmaf(av.x, b0.y, acc[rr][1]);                       \
            acc[rr][2] = fmaf(av.x, b0.z, acc[rr][2]);                       \
            acc[rr][3] = fmaf(av.x, b0.w, acc[rr][3]);                       \
            acc[rr][0] = fmaf(av.y, b1.x, acc[rr][0]);                       \
            acc[rr][1] = fmaf(av.y, b1.y, acc[rr][1]);                       \
            acc[rr][2] = fmaf(av.y, b1.z, acc[rr][2]);                       \
            acc[rr][3] = fmaf(av.y, b1.w, acc[rr][3]);                       \
            acc[rr][0] = fmaf(av.z, b2.x, acc[rr][0]);                       \
            acc[rr][1] = fmaf(av.z, b2.y, acc[rr][1]);                       \
            acc[rr][2] = fmaf(av.z, b2.z, acc[rr][2]);                       \
            acc[rr][3] = fmaf(av.z, b2.w, acc[rr][3]);                       \
            acc[rr][0] = fmaf(av.w, b3.x, acc[rr][0]);                       \
            acc[rr][1] = fmaf(av.w, b3.y, acc[rr][1]);                       \
            acc[rr][2] = fmaf(av.w, b3.z, acc[rr][2]);                       \
            acc[rr][3] = fmaf(av.w, b3.w, acc[rr][3]);
            GEMM_ROW(0, a0)
            GEMM_ROW(1, a1)
            GEMM_ROW(2, a2)
            GEMM_ROW(3, a3)
#undef GEMM_ROW
        }
    }

    // epilogue: attention logits (width-16 shuffle reduce) + H store
    float4 ats = *(const float4*)&att_s[tx * 4];
    float4 atd = *(const float4*)&att_d[tx * 4];
#pragma unroll
    for (int rr = 0; rr < 4; ++rr) {
        int nd = node0 + ty * 4 + rr;
        float vs = acc[rr][0] * ats.x + acc[rr][1] * ats.y +
                   acc[rr][2] * ats.z + acc[rr][3] * ats.w;
        float vd = acc[rr][0] * atd.x + acc[rr][1] * atd.y +
                   acc[rr][2] * atd.z + acc[rr][3] * atd.w;
#pragma unroll
        for (int off = 8; off; off >>= 1) {
            vs += __shfl_xor(vs, off);
            vd += __shfl_xor(vd, off);
        }
        if (nd < n) {
            float4 hv = make_float4(acc[rr][0], acc[rr][1], acc[rr][2], acc[rr][3]);
            *(float4*)&H[(size_t)nd * 64 + tx * 4] = hv;
            if (tx == 0) { As[nd] = vs; Ad[nd] = vd; }
        }
    }
}

// ---------------------------------------------------------------------------
// CSR build: histogram -> scan -> scatter (scatter also emits leaky-relu'd
// per-edge logits so the aggregation passes read them coalesced).
// ---------------------------------------------------------------------------
__global__ void hist_kernel(const int* __restrict__ dst, int e, int* __restrict__ deg)
{
    int i = blockIdx.x * blockDim.x + threadIdx.x;
    if (i < e) atomicAdd(&deg[dst[i]], 1);
}

#define SCAN_B 256
#define SCAN_E 1024  // 4 elems per thread

__global__ __launch_bounds__(SCAN_B) void scan1_kernel(
    const int* __restrict__ deg, int n, int* __restrict__ out /* = rp+1 */,
    int* __restrict__ partials)
{
    __shared__ int sh[SCAN_B];
    const int b = blockIdx.x, t = threadIdx.x;
    const int base = b * SCAN_E + t * 4;
    int v[4];
#pragma unroll
    for (int i = 0; i < 4; ++i) {
        int idx = base + i;
        v[i] = (idx < n) ? deg[idx] : 0;
    }
    v[1] += v[0]; v[2] += v[1]; v[3] += v[2];
    sh[t] = v[3];
    __syncthreads();
    for (int off = 1; off < SCAN_B; off <<= 1) {
        int x = (t >= off) ? sh[t - off] : 0;
        __syncthreads();
        sh[t] += x;
        __syncthreads();
    }
    int excl = (t > 0) ? sh[t - 1] : 0;
#pragma unroll
    for (int i = 0; i < 4; ++i) {
        int idx = base + i;
        if (idx < n) out[idx] = v[i] + excl;  // inclusive scan
    }
    if (t == SCAN_B - 1) partials[b] = sh[t];
}

__global__ void scan2_kernel(int* __restrict__ partials, int nb)
{
    if (threadIdx.x == 0 && blockIdx.x == 0) {
        int run = 0;
        for (int i = 0; i < nb; ++i) {
            int v = partials[i];
            partials[i] = run;
            run += v;
        }
    }
}

__global__ void scan3_kernel(int* __restrict__ rp, int n, const int* __restrict__ partials)
{
    int i = blockIdx.x * blockDim.x + threadIdx.x;
    if (i < n) rp[1 + i] += partials[i >> 10];
    if (i == 0) rp[0] = 0;
}

__global__ void cursor_kernel(const int* __restrict__ rp, int* __restrict__ cursor, int n)
{
    int i = blockIdx.x * blockDim.x + threadIdx.x;
    if (i < n) cursor[i] = rp[i];
}

__global__ void scatter_kernel(const int* __restrict__ src, const int* __restrict__ dst,
                               int e, int* __restrict__ cursor, int* __restrict__ sorted,
                               float* __restrict__ evals,
                               const float* __restrict__ As, const float* __restrict__ Ad)
{
    int i = blockIdx.x * blockDim.x + threadIdx.x;
    if (i < e) {
        int s = src[i];
        int d = dst[i];
        int pos = atomicAdd(&cursor[d], 1);
        sorted[pos] = s;
        float ev = As[s] + Ad[d];
        evals[pos] = (ev >= 0.0f) ? ev : NEG_SLOPE * ev;
    }
}

// ---------------------------------------------------------------------------
// Aggregation: one wave per destination node.
// Pass A: online softmax (max+sum in one pass) over coalesced evals.
// Pass B: weighted gather of H rows, 4 independent accumulators for MLP.
// sorted[i]/evals[i] in pass B are wave-uniform -> scalar loads.
// ---------------------------------------------------------------------------
__global__ __launch_bounds__(256) void aggr_kernel(
    const int* __restrict__ rp, const int* __restrict__ sorted,
    const float* __restrict__ evals,
    const float* __restrict__ Hin, const float* __restrict__ bias,
    float* __restrict__ Out, int n, int relu_flag)
{
    const int lane = threadIdx.x & 63;
    const int wv = threadIdx.x >> 6;
    const float b = bias[lane];

    for (int d = blockIdx.x * 4 + wv; d < n; d += gridDim.x * 4) {
        const int beg = rp[d], end = rp[d + 1];

        // online max+sum (sentinel avoids -inf - -inf NaN)
        float m = -1e30f, s = 0.0f;
        for (int i = beg + lane; i < end; i += 64) {
            float e = evals[i];
            float mn = fmaxf(m, e);
            s = s * __expf(m - mn) + __expf(e - mn);
            m = mn;
        }
#pragma unroll
        for (int off = 32; off; off >>= 1) {
            float mo = __shfl_xor(m, off);
            float so = __shfl_xor(s, off);
            float mn = fmaxf(m, mo);
            s = s * __expf(m - mn) + so * __expf(mo - mn);
            m = mn;
        }
        const float inv = 1.0f / (s + 1e-16f);

        float acc0 = 0.f, acc1 = 0.f, acc2 = 0.f, acc3 = 0.f;
        int i = beg;
        for (; i + 4 <= end; i += 4) {
            int s0 = sorted[i + 0];
            int s1 = sorted[i + 1];
            int s2 = sorted[i + 2];
            int s3 = sorted[i + 3];
            float w0 = __expf(evals[i + 0] - m) * inv;
            float w1 = __expf(evals[i + 1] - m) * inv;
            float w2 = __expf(evals[i + 2] - m) * inv;
            float w3 = __expf(evals[i + 3] - m) * inv;
            acc0 = fmaf(w0, Hin[(size_t)s0 * 64 + lane], acc0);
            acc1 = fmaf(w1, Hin[(size_t)s1 * 64 + lane], acc1);
            acc2 = fmaf(w2, Hin[(size_t)s2 * 64 + lane], acc2);
            acc3 = fmaf(w3, Hin[(size_t)s3 * 64 + lane], acc3);
        }
        for (; i < end; ++i) {
            float w = __expf(evals[i] - m) * inv;
            acc0 = fmaf(w, Hin[(size_t)sorted[i] * 64 + lane], acc0);
        }

        float r = (acc0 + acc1) + (acc2 + acc3) + b;
        if (relu_flag) r = fmaxf(r, 0.0f);
        Out[(size_t)d * 64 + lane] = r;
    }
}

// ---------------------------------------------------------------------------
// Final linear [64 -> 32] + log_softmax. 2 nodes per wave (width-32 groups).
// ---------------------------------------------------------------------------
__global__ __launch_bounds__(256) void lin_lsm_kernel(
    const float* __restrict__ Z, const float* __restrict__ Wl,
    const float* __restrict__ bl, float* __restrict__ out, int n)
{
    __shared__ float Ws[64 * 32];
    __shared__ float bs[32];
    for (int i = threadIdx.x; i < 64 * 32; i += 256) Ws[i] = Wl[i];
    if (threadIdx.x < 32) bs[threadIdx.x] = bl[threadIdx.x];
    __syncthreads();

    const int lane = threadIdx.x & 63;
    const int wv = threadIdx.x >> 6;
    const int half = lane >> 5;
    const int o = lane & 31;

    for (int base = (blockIdx.x * 4 + wv) * 2; base < n; base += gridDim.x * 8) {
        const int nd = base + half;
        float acc = 0.0f;
        if (nd < n) {
            const float* z = Z + (size_t)nd * 64;
#pragma unroll
            for (int k = 0; k < 64; ++k)
                acc = fmaf(z[k], Ws[k * 32 + o], acc);
            acc += bs[o];
        }
        float m = acc;
#pragma unroll
        for (int off = 16; off; off >>= 1) m = fmaxf(m, __shfl_xor(m, off, 32));
        float ex = __expf(acc - m);
        float s = ex;
#pragma unroll
        for (int off = 16; off; off >>= 1) s += __shfl_xor(s, off, 32);
        if (nd < n) out[(size_t)nd * 32 + o] = acc - m - logf(s);
    }
}

// ---------------------------------------------------------------------------
extern "C" void kernel_launch(void* const* d_in, const int* in_sizes, int n_in,
                              void* d_out, int out_size, void* d_ws, size_t ws_size,
                              hipStream_t stream)
{
    const float* x        = (const float*)d_in[0];
    const int*   ei1      = (const int*)d_in[1];
    const int*   ei2      = (const int*)d_in[2];
    const float* W1       = (const float*)d_in[3];
    const float* att_src1 = (const float*)d_in[4];
    const float* att_dst1 = (const float*)d_in[5];
    const float* b1       = (const float*)d_in[6];
    const float* W2       = (const float*)d_in[7];
    const float* att_src2 = (const float*)d_in[8];
    const float* att_dst2 = (const float*)d_in[9];
    const float* b2       = (const float*)d_in[10];
    const float* Wlin     = (const float*)d_in[11];
    const float* blin     = (const float*)d_in[12];
    float* out = (float*)d_out;

    const int n = in_sizes[0] / 128;   // 100000
    const int e = in_sizes[1] / 2;     // 1600000

    // workspace layout
    size_t off = 0;
    auto alloc = [&](size_t bytes) {
        void* p = (char*)d_ws + off;
        off += (bytes + 255) & ~(size_t)255;
        return p;
    };
    float* bufH  = (float*)alloc((size_t)n * 64 * 4);
    float* bufZ  = (float*)alloc((size_t)n * 64 * 4);
    float* As    = (float*)alloc((size_t)n * 4);
    float* Ad    = (float*)alloc((size_t)n * 4);
    int* deg     = (int*)alloc((size_t)n * 4);
    int* rp      = (int*)alloc((size_t)(n + 1) * 4);
    int* cursor  = (int*)alloc((size_t)n * 4);
    int* partials= (int*)alloc(256 * 4);
    int* sorted  = (int*)alloc((size_t)e * 4);
    float* evals = (float*)alloc((size_t)e * 4);

    const int nb_scan = (n + SCAN_E - 1) / SCAN_E;
    const int gE = (e + 255) / 256;
    const int gN = (n + 255) / 256;
    const int gTile = (n + 63) / 64;    // gemm tiles
    const int gWave = (n + 3) / 4;      // one wave per node, 4 waves/block

    // ---------------- Layer 1 ----------------
    gemm_tile<128><<<gTile, 256, 0, stream>>>(x, W1, att_src1, att_dst1, bufH, As, Ad, n);

    hipMemsetAsync(deg, 0, (size_t)n * 4, stream);
    hist_kernel<<<gE, 256, 0, stream>>>(ei1 + e, e, deg);
    scan1_kernel<<<nb_scan, SCAN_B, 0, stream>>>(deg, n, rp + 1, partials);
    scan2_kernel<<<1, 64, 0, stream>>>(partials, nb_scan);
    scan3_kernel<<<gN, 256, 0, stream>>>(rp, n, partials);
    cursor_kernel<<<gN, 256, 0, stream>>>(rp, cursor, n);
    scatter_kernel<<<gE, 256, 0, stream>>>(ei1, ei1 + e, e, cursor, sorted, evals, As, Ad);

    aggr_kernel<<<gWave, 256, 0, stream>>>(rp, sorted, evals, bufH, b1, bufZ, n, 1);

    // ---------------- Layer 2 ----------------
    gemm_tile<64><<<gTile, 256, 0, stream>>>(bufZ, W2, att_src2, att_dst2, bufH, As, Ad, n);

    hipMemsetAsync(deg, 0, (size_t)n * 4, stream);
    hist_kernel<<<gE, 256, 0, stream>>>(ei2 + e, e, deg);
    scan1_kernel<<<nb_scan, SCAN_B, 0, stream>>>(deg, n, rp + 1, partials);
    scan2_kernel<<<1, 64, 0, stream>>>(partials, nb_scan);
    scan3_kernel<<<gN, 256, 0, stream>>>(rp, n, partials);
    cursor_kernel<<<gN, 256, 0, stream>>>(rp, cursor, n);
    scatter_kernel<<<gE, 256, 0, stream>>>(ei2, ei2 + e, e, cursor, sorted, evals, As, Ad);

    aggr_kernel<<<gWave, 256, 0, stream>>>(rp, sorted, evals, bufH, b2, bufZ, n, 0);

    // ---------------- Final linear + log_softmax ----------------
    const int gLSM = (n + 7) / 8;
    lin_lsm_kernel<<<gLSM, 256, 0, stream>>>(bufZ, Wlin, blin, out, n);
}

// Round 3
// 691.233 us; speedup vs baseline: 1.7920x; 1.1027x over previous
//
#include <hip/hip_runtime.h>
#include <math.h>

#define NEG_SLOPE 0.2f
#define NXCD 8

// ---------------------------------------------------------------------------
// Register-tiled GEMM + fused attention logits.
//   H[n,64] = X[n,K] @ W[K,64];  As[n] = H.att_s;  Ad[n] = H.att_d
// Block: 256 threads -> tile 64 nodes x 64 features, per-thread 4x4 acc.
// ---------------------------------------------------------------------------
template <int K>
__global__ __launch_bounds__(256) void gemm_tile(
    const float* __restrict__ X, const float* __restrict__ W,
    const float* __restrict__ att_s, const float* __restrict__ att_d,
    float* __restrict__ H, float* __restrict__ As, float* __restrict__ Ad,
    int n)
{
    constexpr int XP = K + 4;
    constexpr int BK = 64;
    __shared__ float Xs[64 * XP];
    __shared__ float Ws[BK * 64];

    const int tid = threadIdx.x;
    const int node0 = blockIdx.x * 64;

    for (int i4 = tid; i4 < 64 * (K / 4); i4 += 256) {
        int r = i4 / (K / 4);
        int c = (i4 % (K / 4)) * 4;
        int nd = node0 + r;
        float4 v = make_float4(0.f, 0.f, 0.f, 0.f);
        if (nd < n) v = *(const float4*)&X[(size_t)nd * K + c];
        *(float4*)&Xs[r * XP + c] = v;
    }

    const int tx = tid & 15;   // feature group
    const int ty = tid >> 4;   // node group

    float acc[4][4];
#pragma unroll
    for (int r = 0; r < 4; ++r)
#pragma unroll
        for (int f = 0; f < 4; ++f) acc[r][f] = 0.0f;

    for (int kc = 0; kc < K; kc += BK) {
        __syncthreads();
        for (int i = tid; i < BK * 64; i += 256) Ws[i] = W[kc * 64 + i];
        __syncthreads();

        for (int k = 0; k < BK; k += 4) {
            float4 a0 = *(const float4*)&Xs[(ty * 4 + 0) * XP + kc + k];
            float4 a1 = *(const float4*)&Xs[(ty * 4 + 1) * XP + kc + k];
            float4 a2 = *(const float4*)&Xs[(ty * 4 + 2) * XP + kc + k];
            float4 a3 = *(const float4*)&Xs[(ty * 4 + 3) * XP + kc + k];
            float4 b0 = *(const float4*)&Ws[(k + 0) * 64 + tx * 4];
            float4 b1 = *(const float4*)&Ws[(k + 1) * 64 + tx * 4];
            float4 b2 = *(const float4*)&Ws[(k + 2) * 64 + tx * 4];
            float4 b3 = *(const float4*)&Ws[(k + 3) * 64 + tx * 4];
#define GEMM_ROW(rr, av)                                                     \
            acc[rr][0] = fmaf(av.x, b0.x, acc[rr][0]);                       \
            acc[rr][1] = fmaf(av.x, b0.y, acc[rr][1]);                       \
            acc[rr][2] = fmaf(av.x, b0.z, acc[rr][2]);                       \
            acc[rr][3] = fmaf(av.x, b0.w, acc[rr][3]);                       \
            acc[rr][0] = fmaf(av.y, b1.x, acc[rr][0]);                       \
            acc[rr][1] = fmaf(av.y, b1.y, acc[rr][1]);                       \
            acc[rr][2] = fmaf(av.y, b1.z, acc[rr][2]);                       \
            acc[rr][3] = fmaf(av.y, b1.w, acc[rr][3]);                       \
            acc[rr][0] = fmaf(av.z, b2.x, acc[rr][0]);                       \
            acc[rr][1] = fmaf(av.z, b2.y, acc[rr][1]);                       \
            acc[rr][2] = fmaf(av.z, b2.z, acc[rr][2]);                       \
            acc[rr][3] = fmaf(av.z, b2.w, acc[rr][3]);                       \
            acc[rr][0] = fmaf(av.w, b3.x, acc[rr][0]);                       \
            acc[rr][1] = fmaf(av.w, b3.y, acc[rr][1]);                       \
            acc[rr][2] = fmaf(av.w, b3.z, acc[rr][2]);                       \
            acc[rr][3] = fmaf(av.w, b3.w, acc[rr][3]);
            GEMM_ROW(0, a0)
            GEMM_ROW(1, a1)
            GEMM_ROW(2, a2)
            GEMM_ROW(3, a3)
#undef GEMM_ROW
        }
    }

    float4 ats = *(const float4*)&att_s[tx * 4];
    float4 atd = *(const float4*)&att_d[tx * 4];
#pragma unroll
    for (int rr = 0; rr < 4; ++rr) {
        int nd = node0 + ty * 4 + rr;
        float vs = acc[rr][0] * ats.x + acc[rr][1] * ats.y +
                   acc[rr][2] * ats.z + acc[rr][3] * ats.w;
        float vd = acc[rr][0] * atd.x + acc[rr][1] * atd.y +
                   acc[rr][2] * atd.z + acc[rr][3] * atd.w;
#pragma unroll
        for (int off = 8; off; off >>= 1) {
            vs += __shfl_xor(vs, off);
            vd += __shfl_xor(vd, off);
        }
        if (nd < n) {
            float4 hv = make_float4(acc[rr][0], acc[rr][1], acc[rr][2], acc[rr][3]);
            *(float4*)&H[(size_t)nd * 64 + tx * 4] = hv;
            if (tx == 0) { As[nd] = vs; Ad[nd] = vd; }
        }
    }
}

// ---------------------------------------------------------------------------
// CSR build: histogram -> scan -> XCD-local scatter
// ---------------------------------------------------------------------------
__global__ void hist_kernel(const int* __restrict__ dst, int e, int* __restrict__ deg)
{
    int i = blockIdx.x * blockDim.x + threadIdx.x;
    if (i < e) atomicAdd(&deg[__builtin_nontemporal_load(&dst[i])], 1);
}

#define SCAN_B 256
#define SCAN_E 1024  // 4 elems per thread

__global__ __launch_bounds__(SCAN_B) void scan1_kernel(
    const int* __restrict__ deg, int n, int* __restrict__ out /* = rp+1 */,
    int* __restrict__ partials)
{
    __shared__ int sh[SCAN_B];
    const int b = blockIdx.x, t = threadIdx.x;
    const int base = b * SCAN_E + t * 4;
    int v[4];
#pragma unroll
    for (int i = 0; i < 4; ++i) {
        int idx = base + i;
        v[i] = (idx < n) ? deg[idx] : 0;
    }
    v[1] += v[0]; v[2] += v[1]; v[3] += v[2];
    sh[t] = v[3];
    __syncthreads();
    for (int off = 1; off < SCAN_B; off <<= 1) {
        int x = (t >= off) ? sh[t - off] : 0;
        __syncthreads();
        sh[t] += x;
        __syncthreads();
    }
    int excl = (t > 0) ? sh[t - 1] : 0;
#pragma unroll
    for (int i = 0; i < 4; ++i) {
        int idx = base + i;
        if (idx < n) out[idx] = v[i] + excl;  // inclusive scan
    }
    if (t == SCAN_B - 1) partials[b] = sh[t];
}

// parallel single-block exclusive scan of partials (nb <= 256)
__global__ __launch_bounds__(256) void scan2_kernel(int* __restrict__ partials, int nb)
{
    __shared__ int sh[256];
    const int t = threadIdx.x;
    int v = (t < nb) ? partials[t] : 0;
    sh[t] = v;
    __syncthreads();
    for (int off = 1; off < 256; off <<= 1) {
        int x = (t >= off) ? sh[t - off] : 0;
        __syncthreads();
        sh[t] += x;
        __syncthreads();
    }
    if (t < nb) partials[t] = (t > 0) ? sh[t - 1] : 0;  // exclusive
}

// adds block offsets; also initializes cursor[] = final rp[]
__global__ void scan3_kernel(int* __restrict__ rp, int* __restrict__ cursor,
                             int n, const int* __restrict__ partials)
{
    int i = blockIdx.x * blockDim.x + threadIdx.x;
    if (i < n) {
        int v = rp[1 + i] + partials[i >> 10];
        rp[1 + i] = v;
        if (i + 1 < n) cursor[i + 1] = v;
    }
    if (i == 0) { rp[0] = 0; cursor[0] = 0; }
}

// XCD-local scatter: blocks with the same (blockIdx & 7) form a group that
// handles dst range [g*lo_div, (g+1)*lo_div). Each group scans the full edge
// list (nontemporal, L3-resident) and writes packed {src, leakyrelu(logit)}
// int2 records into its group's contiguous region, which fits the XCD's 4MB
// L2 -> lines accumulate all ~8 record writes before writeback.
__global__ __launch_bounds__(256) void scatter_kernel(
    const int* __restrict__ src, const int* __restrict__ dst, int e,
    int* __restrict__ cursor, int2* __restrict__ rec,
    const float* __restrict__ As, const float* __restrict__ Ad, int lo_div)
{
    const int g = blockIdx.x & (NXCD - 1);
    const int gi = blockIdx.x >> 3;
    const int nblk = gridDim.x >> 3;
    const int lo = g * lo_div, hi = lo + lo_div;

    for (int i = gi * 256 + threadIdx.x; i < e; i += nblk * 256) {
        int d = __builtin_nontemporal_load(&dst[i]);
        if (d >= lo && d < hi) {
            int s = __builtin_nontemporal_load(&src[i]);
            float ev = As[s] + Ad[d];
            ev = (ev >= 0.0f) ? ev : NEG_SLOPE * ev;
            int pos = atomicAdd(&cursor[d], 1);
            int2 r;
            r.x = s;
            r.y = __float_as_int(ev);
            rec[pos] = r;
        }
    }
}

// ---------------------------------------------------------------------------
// Aggregation: one wave per destination node, XCD-swizzled to match the
// scatter's range->XCD mapping.
// Pass A: online softmax over coalesced rec[].y.
// Pass B: weighted gather of H rows, 4 independent accumulator chains.
// ---------------------------------------------------------------------------
__global__ __launch_bounds__(256) void aggr_kernel(
    const int* __restrict__ rp, const int2* __restrict__ rec,
    const float* __restrict__ Hin, const float* __restrict__ bias,
    float* __restrict__ Out, int n, int lo_div, int relu_flag)
{
    const int lane = threadIdx.x & 63;
    const int wv = threadIdx.x >> 6;
    const float b = bias[lane];

    const int g = blockIdx.x & (NXCD - 1);
    const int gi = blockIdx.x >> 3;
    const int ngb = gridDim.x >> 3;
    const int lo = g * lo_div;
    const int hi = min(lo + lo_div, n);

    for (int d = lo + gi * 4 + wv; d < hi; d += ngb * 4) {
        const int beg = rp[d], end = rp[d + 1];

        // online max+sum (sentinel avoids -inf - -inf NaN)
        float m = -1e30f, s = 0.0f;
        for (int i = beg + lane; i < end; i += 64) {
            float e = __int_as_float(rec[i].y);
            float mn = fmaxf(m, e);
            s = s * __expf(m - mn) + __expf(e - mn);
            m = mn;
        }
#pragma unroll
        for (int off = 32; off; off >>= 1) {
            float mo = __shfl_xor(m, off);
            float so = __shfl_xor(s, off);
            float mn = fmaxf(m, mo);
            s = s * __expf(m - mn) + so * __expf(mo - mn);
            m = mn;
        }
        const float inv = 1.0f / (s + 1e-16f);

        float acc0 = 0.f, acc1 = 0.f, acc2 = 0.f, acc3 = 0.f;
        int i = beg;
        for (; i + 4 <= end; i += 4) {
            int2 r0 = rec[i + 0];
            int2 r1 = rec[i + 1];
            int2 r2 = rec[i + 2];
            int2 r3 = rec[i + 3];
            float w0 = __expf(__int_as_float(r0.y) - m) * inv;
            float w1 = __expf(__int_as_float(r1.y) - m) * inv;
            float w2 = __expf(__int_as_float(r2.y) - m) * inv;
            float w3 = __expf(__int_as_float(r3.y) - m) * inv;
            acc0 = fmaf(w0, Hin[(size_t)r0.x * 64 + lane], acc0);
            acc1 = fmaf(w1, Hin[(size_t)r1.x * 64 + lane], acc1);
            acc2 = fmaf(w2, Hin[(size_t)r2.x * 64 + lane], acc2);
            acc3 = fmaf(w3, Hin[(size_t)r3.x * 64 + lane], acc3);
        }
        for (; i < end; ++i) {
            int2 r = rec[i];
            float w = __expf(__int_as_float(r.y) - m) * inv;
            acc0 = fmaf(w, Hin[(size_t)r.x * 64 + lane], acc0);
        }

        float r = (acc0 + acc1) + (acc2 + acc3) + b;
        if (relu_flag) r = fmaxf(r, 0.0f);
        Out[(size_t)d * 64 + lane] = r;
    }
}

// ---------------------------------------------------------------------------
// Final linear [64 -> 32] + log_softmax. 2 nodes per wave.
// ---------------------------------------------------------------------------
__global__ __launch_bounds__(256) void lin_lsm_kernel(
    const float* __restrict__ Z, const float* __restrict__ Wl,
    const float* __restrict__ bl, float* __restrict__ out, int n)
{
    __shared__ float Ws[64 * 32];
    __shared__ float bs[32];
    for (int i = threadIdx.x; i < 64 * 32; i += 256) Ws[i] = Wl[i];
    if (threadIdx.x < 32) bs[threadIdx.x] = bl[threadIdx.x];
    __syncthreads();

    const int lane = threadIdx.x & 63;
    const int wv = threadIdx.x >> 6;
    const int half = lane >> 5;
    const int o = lane & 31;

    for (int base = (blockIdx.x * 4 + wv) * 2; base < n; base += gridDim.x * 8) {
        const int nd = base + half;
        float acc = 0.0f;
        if (nd < n) {
            const float* z = Z + (size_t)nd * 64;
#pragma unroll
            for (int k = 0; k < 64; ++k)
                acc = fmaf(z[k], Ws[k * 32 + o], acc);
            acc += bs[o];
        }
        float m = acc;
#pragma unroll
        for (int off = 16; off; off >>= 1) m = fmaxf(m, __shfl_xor(m, off, 32));
        float ex = __expf(acc - m);
        float s = ex;
#pragma unroll
        for (int off = 16; off; off >>= 1) s += __shfl_xor(s, off, 32);
        if (nd < n) out[(size_t)nd * 32 + o] = acc - m - logf(s);
    }
}

// ---------------------------------------------------------------------------
extern "C" void kernel_launch(void* const* d_in, const int* in_sizes, int n_in,
                              void* d_out, int out_size, void* d_ws, size_t ws_size,
                              hipStream_t stream)
{
    const float* x        = (const float*)d_in[0];
    const int*   ei1      = (const int*)d_in[1];
    const int*   ei2      = (const int*)d_in[2];
    const float* W1       = (const float*)d_in[3];
    const float* att_src1 = (const float*)d_in[4];
    const float* att_dst1 = (const float*)d_in[5];
    const float* b1       = (const float*)d_in[6];
    const float* W2       = (const float*)d_in[7];
    const float* att_src2 = (const float*)d_in[8];
    const float* att_dst2 = (const float*)d_in[9];
    const float* b2       = (const float*)d_in[10];
    const float* Wlin     = (const float*)d_in[11];
    const float* blin     = (const float*)d_in[12];
    float* out = (float*)d_out;

    const int n = in_sizes[0] / 128;   // 100000
    const int e = in_sizes[1] / 2;     // 1600000

    size_t off = 0;
    auto alloc = [&](size_t bytes) {
        void* p = (char*)d_ws + off;
        off += (bytes + 255) & ~(size_t)255;
        return p;
    };
    float* bufH  = (float*)alloc((size_t)n * 64 * 4);
    float* bufZ  = (float*)alloc((size_t)n * 64 * 4);
    float* As    = (float*)alloc((size_t)n * 4);
    float* Ad    = (float*)alloc((size_t)n * 4);
    int* deg     = (int*)alloc((size_t)n * 4);
    int* rp      = (int*)alloc((size_t)(n + 1) * 4);
    int* cursor  = (int*)alloc((size_t)n * 4);
    int* partials= (int*)alloc(256 * 4);
    int2* rec    = (int2*)alloc((size_t)e * 8);

    const int nb_scan = (n + SCAN_E - 1) / SCAN_E;
    const int gE = (e + 255) / 256;
    const int gN = (n + 255) / 256;
    const int gTile = (n + 63) / 64;
    const int lo_div = (n + NXCD - 1) / NXCD;
    const int gAggr = NXCD * ((lo_div + 3) / 4);
    const int gScat = 2048;  // multiple of 8; 8 blocks/CU

    // ---------------- Layer 1 ----------------
    gemm_tile<128><<<gTile, 256, 0, stream>>>(x, W1, att_src1, att_dst1, bufH, As, Ad, n);

    hipMemsetAsync(deg, 0, (size_t)n * 4, stream);
    hist_kernel<<<gE, 256, 0, stream>>>(ei1 + e, e, deg);
    scan1_kernel<<<nb_scan, SCAN_B, 0, stream>>>(deg, n, rp + 1, partials);
    scan2_kernel<<<1, 256, 0, stream>>>(partials, nb_scan);
    scan3_kernel<<<gN, 256, 0, stream>>>(rp, cursor, n, partials);
    scatter_kernel<<<gScat, 256, 0, stream>>>(ei1, ei1 + e, e, cursor, rec, As, Ad, lo_div);

    aggr_kernel<<<gAggr, 256, 0, stream>>>(rp, rec, bufH, b1, bufZ, n, lo_div, 1);

    // ---------------- Layer 2 ----------------
    gemm_tile<64><<<gTile, 256, 0, stream>>>(bufZ, W2, att_src2, att_dst2, bufH, As, Ad, n);

    hipMemsetAsync(deg, 0, (size_t)n * 4, stream);
    hist_kernel<<<gE, 256, 0, stream>>>(ei2 + e, e, deg);
    scan1_kernel<<<nb_scan, SCAN_B, 0, stream>>>(deg, n, rp + 1, partials);
    scan2_kernel<<<1, 256, 0, stream>>>(partials, nb_scan);
    scan3_kernel<<<gN, 256, 0, stream>>>(rp, cursor, n, partials);
    scatter_kernel<<<gScat, 256, 0, stream>>>(ei2, ei2 + e, e, cursor, rec, As, Ad, lo_div);

    aggr_kernel<<<gAggr, 256, 0, stream>>>(rp, rec, bufH, b2, bufZ, n, lo_div, 0);

    // ---------------- Final linear + log_softmax ----------------
    const int gLSM = (n + 7) / 8;
    lin_lsm_kernel<<<gLSM, 256, 0, stream>>>(bufZ, Wlin, blin, out, n);
}